// Round 2
// baseline (1460.518 us; speedup 1.0000x reference)
//
#include <hip/hip_runtime.h>
#include <hip/hip_bf16.h>
#include <math.h>

typedef __bf16 bf16_t;
typedef __bf16 bf16x2_t __attribute__((ext_vector_type(2)));
typedef __bf16 bf16x4_t __attribute__((ext_vector_type(4)));
typedef __bf16 bf16x8_t __attribute__((ext_vector_type(8)));
typedef float f32x4_t __attribute__((ext_vector_type(4)));

#define B_N 1024
#define L_N 1024
#define T_N 32
#define H_N 2048
#define K_TOP 64
#define O_N 256
#define NCOL (T_N * H_N) /* 65536 */

// ---------------- conversion: x -> bf16 ----------------
__global__ __launch_bounds__(256) void cvt_x_kernel(const float* __restrict__ x,
                                                    bf16_t* __restrict__ xb) {
  int i = (blockIdx.x * 256 + threadIdx.x) * 4;
  float4 v = *(const float4*)(x + i);
  bf16x4_t o;
  o[0] = (bf16_t)v.x; o[1] = (bf16_t)v.y; o[2] = (bf16_t)v.z; o[3] = (bf16_t)v.w;
  *(bf16x4_t*)(xb + i) = o;
}

// -------- conversion+transpose: Wt [T,L,H] f32 -> WT [T,H,L] bf16 --------
__global__ __launch_bounds__(256) void cvt_w_kernel(const float* __restrict__ W,
                                                    bf16_t* __restrict__ WT) {
  __shared__ float tile[64][65];
  int t = blockIdx.z;
  int h0 = blockIdx.x * 64;
  int l0 = blockIdx.y * 64;
  const float* src = W + (size_t)t * L_N * H_N;
  int hx = threadIdx.x & 63;
  int ly = threadIdx.x >> 6;
#pragma unroll
  for (int r = 0; r < 64; r += 4)
    tile[ly + r][hx] = src[(size_t)(l0 + ly + r) * H_N + h0 + hx];
  __syncthreads();
  bf16_t* dst = WT + (size_t)t * H_N * L_N;
  int lx = (threadIdx.x & 31) * 2;
  int hy = threadIdx.x >> 5;
#pragma unroll
  for (int r = 0; r < 64; r += 8) {
    int h = hy + r;
    bf16x2_t o;
    o[0] = (bf16_t)tile[lx][h];
    o[1] = (bf16_t)tile[lx + 1][h];
    *(bf16x2_t*)(dst + (size_t)(h0 + h) * L_N + l0 + lx) = o;
  }
}

// ---------------- GEMM1: hidden[b, t*2048+h] = sum_l x[b,l]*W[t,l,h] ----------------
#define BM 128
#define BN 128
#define BK 32

__device__ __forceinline__ void async_load16(const void* g, void* l) {
  __builtin_amdgcn_global_load_lds((const __attribute__((address_space(1))) void*)g,
                                   (__attribute__((address_space(3))) void*)l,
                                   16, 0, 0);
}

template <typename HT>
__global__ __launch_bounds__(256) void gemm1_kernel(const bf16_t* __restrict__ Xb,
                                                    const bf16_t* __restrict__ WT,
                                                    HT* __restrict__ hidden) {
  __shared__ bf16_t As[BM][BK]; // [m][k], row = 64 B
  __shared__ bf16_t Bs[BN][BK]; // [n][k], row = 64 B  (WT is already [n][k] in global)
  int tid = threadIdx.x;
  int wave = tid >> 6;
  int lane = tid & 63;
  int bid = blockIdx.x;
  int m0 = (bid & 7) * BM;      // 8 row tiles over B=1024
  int nbase = (bid >> 3) * BN;  // 512 col tiles over T*H=65536

  const bf16_t* Aptr = Xb + (size_t)m0 * L_N;
  const bf16_t* Bptr = WT + (size_t)nbase * L_N;

  // staging: lane i copies 16 B; wave covers 16 contiguous 64 B LDS rows
  int srow = lane >> 2;
  int scol = lane & 3;
  size_t soff = (size_t)(wave * 16 + srow) * L_N + scol * 8;

  f32x4_t acc[4][4];
  f32x4_t zero = {0.f, 0.f, 0.f, 0.f};
#pragma unroll
  for (int i = 0; i < 4; i++)
#pragma unroll
    for (int j = 0; j < 4; j++) acc[i][j] = zero;

  int wm = wave >> 1, wn = wave & 1;
  int fr = lane & 15;
  int fq = lane >> 4;

  for (int k0 = 0; k0 < L_N; k0 += BK) {
    const bf16_t* ga = Aptr + soff + k0;
    const bf16_t* gb = Bptr + soff + k0;
    async_load16(ga, &As[wave * 16][0]);
    async_load16(ga + 64 * L_N, &As[64 + wave * 16][0]);
    async_load16(gb, &Bs[wave * 16][0]);
    async_load16(gb + 64 * L_N, &Bs[64 + wave * 16][0]);
    __syncthreads();
    bf16x8_t af[4], bfv[4];
#pragma unroll
    for (int i = 0; i < 4; i++)
      af[i] = *(const bf16x8_t*)&As[wm * 64 + i * 16 + fr][fq * 8];
#pragma unroll
    for (int j = 0; j < 4; j++)
      bfv[j] = *(const bf16x8_t*)&Bs[wn * 64 + j * 16 + fr][fq * 8];
#pragma unroll
    for (int i = 0; i < 4; i++)
#pragma unroll
      for (int j = 0; j < 4; j++)
        acc[i][j] = __builtin_amdgcn_mfma_f32_16x16x32_bf16(af[i], bfv[j], acc[i][j], 0, 0, 0);
    __syncthreads();
  }

  // C/D layout: col = lane&15, row = (lane>>4)*4 + r  [verified m89/m91]
#pragma unroll
  for (int i = 0; i < 4; i++) {
    int gm = m0 + wm * 64 + i * 16 + fq * 4;
#pragma unroll
    for (int j = 0; j < 4; j++) {
      int gn = nbase + wn * 64 + j * 16 + fr;
      HT* outp = hidden + (size_t)gm * NCOL + gn;
#pragma unroll
      for (int r = 0; r < 4; r++) outp[(size_t)r * NCOL] = (HT)acc[i][j][r];
    }
  }
}

// ---------------- fused top-64 + dense + GELU + LN (rewritten R1) ----------------
// One wave per (b,t) row; waves fully independent (no __syncthreads).

__device__ __forceinline__ float wave_reduce_sum(float v) {
#pragma unroll
  for (int off = 32; off > 0; off >>= 1) v += __shfl_xor(v, off);
  return v;
}

// order-preserving float->uint key and inverse
__device__ __forceinline__ unsigned f2key(float f) {
  unsigned u = __float_as_uint(f);
  return u ^ ((u >> 31) ? 0xFFFFFFFFu : 0x80000000u);
}
__device__ __forceinline__ float key2f(unsigned k) {
  return __uint_as_float(k ^ ((k >> 31) ? 0x80000000u : 0xFFFFFFFFu));
}

__device__ __forceinline__ int lanes_below(unsigned long long m) {
  return (int)__builtin_amdgcn_mbcnt_hi((unsigned)(m >> 32),
                                        __builtin_amdgcn_mbcnt_lo((unsigned)m, 0u));
}

__device__ __forceinline__ void load_keys(const float* __restrict__ row, int lane,
                                          unsigned key[32]) {
  const float4* r4 = (const float4*)row;
  float4 v[8];
#pragma unroll
  for (int q = 0; q < 8; q++) v[q] = r4[lane + 64 * q];
#pragma unroll
  for (int q = 0; q < 8; q++) {
    key[q * 4 + 0] = f2key(v[q].x);
    key[q * 4 + 1] = f2key(v[q].y);
    key[q * 4 + 2] = f2key(v[q].z);
    key[q * 4 + 3] = f2key(v[q].w);
  }
}

__device__ __forceinline__ void load_keys(const bf16_t* __restrict__ row, int lane,
                                          unsigned key[32]) {
  const bf16x8_t* r8 = (const bf16x8_t*)row;
  bf16x8_t v[4];
#pragma unroll
  for (int q = 0; q < 4; q++) v[q] = r8[lane + 64 * q];
#pragma unroll
  for (int q = 0; q < 4; q++)
#pragma unroll
    for (int j = 0; j < 8; j++) key[q * 8 + j] = f2key((float)v[q][j]);
}

template <typename HT>
__global__ __launch_bounds__(256, 4) void topk_tail_kernel(
    const HT* __restrict__ hidden, const float* __restrict__ Wd,
    const float* __restrict__ bd, const float* __restrict__ gamma,
    const float* __restrict__ beta, float* __restrict__ out) {
  __shared__ unsigned slots[4][K_TOP];
  int t = blockIdx.y;
  int wave = threadIdx.x >> 6;
  int lane = threadIdx.x & 63;
  int b = blockIdx.x * 4 + wave;

  unsigned key[32];
  load_keys(hidden + (size_t)b * NCOL + (size_t)t * H_N, lane, key);

  // exact 64th-largest key: largest thr with count(key >= thr) >= 64
  unsigned thr = 0;
  for (int bit = 31; bit >= 0; --bit) {
    unsigned cand = thr | (1u << bit);
    int c = 0;
#pragma unroll
    for (int i = 0; i < 32; i++) c += (int)__popcll(__ballot(key[i] >= cand));
    if (c >= K_TOP) thr = cand; // wave-uniform
  }

  // compaction via ballot prefix (no atomics, wave-local LDS only)
  int base = 0;
#pragma unroll
  for (int i = 0; i < 32; i++) {
    bool p = key[i] > thr;
    unsigned long long m = __ballot(p);
    if (p) slots[wave][base + lanes_below(m)] = key[i];
    base += (int)__popcll(m);
  }
#pragma unroll
  for (int i = 0; i < 32; i++) {
    bool p = key[i] == thr;
    unsigned long long m = __ballot(p);
    if (p) {
      int pos = base + lanes_below(m);
      if (pos < K_TOP) slots[wave][pos] = key[i];
    }
    base += (int)__popcll(m);
  }

  // 64-lane register bitonic sort, descending (unsigned keys)
  unsigned g = slots[wave][lane];
#pragma unroll
  for (int k = 2; k <= 64; k <<= 1) {
#pragma unroll
    for (int j = k >> 1; j > 0; j >>= 1) {
      unsigned other = (unsigned)__shfl_xor((int)g, j);
      bool keep_max = (((lane & k) == 0) != ((lane & j) != 0));
      unsigned mx = g > other ? g : other;
      unsigned mn = g > other ? other : g;
      g = keep_max ? mx : mn;
    }
  }
  float gv = key2f(g); // lane holds g_sorted[lane]

  // dense: y[n] = sum_k g_k * Wd[t,k,n] + b[t,n]   (fp32, fully unrolled)
  const float* wt = Wd + (size_t)t * K_TOP * O_N;
  float y0 = bd[t * O_N + lane];
  float y1 = bd[t * O_N + 64 + lane];
  float y2 = bd[t * O_N + 128 + lane];
  float y3 = bd[t * O_N + 192 + lane];
#pragma unroll
  for (int k = 0; k < K_TOP; k++) {
    float gk = __shfl(gv, k); // literal k -> v_readlane broadcast
    const float* wr = wt + k * O_N + lane;
    y0 = fmaf(gk, wr[0], y0);
    y1 = fmaf(gk, wr[64], y1);
    y2 = fmaf(gk, wr[128], y2);
    y3 = fmaf(gk, wr[192], y3);
  }
  // exact GELU
  const float is2 = 0.70710678118654752f;
  y0 = 0.5f * y0 * (1.f + erff(y0 * is2));
  y1 = 0.5f * y1 * (1.f + erff(y1 * is2));
  y2 = 0.5f * y2 * (1.f + erff(y2 * is2));
  y3 = 0.5f * y3 * (1.f + erff(y3 * is2));
  // LayerNorm over 256
  float mean = wave_reduce_sum(y0 + y1 + y2 + y3) * (1.f / 256.f);
  float d0 = y0 - mean, d1 = y1 - mean, d2 = y2 - mean, d3 = y3 - mean;
  float var = wave_reduce_sum(d0 * d0 + d1 * d1 + d2 * d2 + d3 * d3) * (1.f / 256.f);
  float rstd = rsqrtf(var + 1e-6f);
  float* op = out + (size_t)b * (T_N * O_N) + (size_t)t * O_N;
  const float* gm = gamma + t * O_N;
  const float* bt = beta + t * O_N;
  op[lane] = d0 * rstd * gm[lane] + bt[lane];
  op[64 + lane] = d1 * rstd * gm[64 + lane] + bt[64 + lane];
  op[128 + lane] = d2 * rstd * gm[128 + lane] + bt[128 + lane];
  op[192 + lane] = d3 * rstd * gm[192 + lane] + bt[192 + lane];
}

// ---------------- launch ----------------
extern "C" void kernel_launch(void* const* d_in, const int* in_sizes, int n_in,
                              void* d_out, int out_size, void* d_ws, size_t ws_size,
                              hipStream_t stream) {
  const float* x = (const float*)d_in[0];
  const float* Wt = (const float*)d_in[1];
  const float* Wd = (const float*)d_in[2];
  const float* bd = (const float*)d_in[3];
  const float* gamma = (const float*)d_in[4];
  const float* beta = (const float*)d_in[5];
  float* out = (float*)d_out;

  char* ws = (char*)d_ws;
  size_t sz_wt = (size_t)T_N * H_N * L_N * 2; // 128 MB
  size_t sz_x = (size_t)B_N * L_N * 2;        // 2 MB
  size_t off_h = sz_wt + sz_x;
  size_t sz_h_f32 = (size_t)B_N * NCOL * 4;   // 256 MB

  bf16_t* WTb = (bf16_t*)ws;
  bf16_t* Xb = (bf16_t*)(ws + sz_wt);

  cvt_x_kernel<<<B_N * L_N / 1024, 256, 0, stream>>>(x, Xb);
  cvt_w_kernel<<<dim3(H_N / 64, L_N / 64, T_N), 256, 0, stream>>>(Wt, WTb);

  if (ws_size >= off_h + sz_h_f32) {
    float* hidden = (float*)(ws + off_h);
    gemm1_kernel<float><<<4096, 256, 0, stream>>>(Xb, WTb, hidden);
    topk_tail_kernel<float><<<dim3(B_N / 4, T_N), 256, 0, stream>>>(
        hidden, Wd, bd, gamma, beta, out);
  } else { // fall back to bf16 hidden (270 MB total ws)
    bf16_t* hidden = (bf16_t*)(ws + off_h);
    gemm1_kernel<bf16_t><<<4096, 256, 0, stream>>>(Xb, WTb, hidden);
    topk_tail_kernel<bf16_t><<<dim3(B_N / 4, T_N), 256, 0, stream>>>(
        hidden, Wd, bd, gamma, beta, out);
  }
}

// Round 3
// 1079.686 us; speedup vs baseline: 1.3527x; 1.3527x over previous
//
#include <hip/hip_runtime.h>
#include <hip/hip_bf16.h>
#include <math.h>

typedef __bf16 bf16_t;
typedef __bf16 bf16x2_t __attribute__((ext_vector_type(2)));
typedef __bf16 bf16x4_t __attribute__((ext_vector_type(4)));
typedef __bf16 bf16x8_t __attribute__((ext_vector_type(8)));
typedef float f32x4_t __attribute__((ext_vector_type(4)));

#define B_N 1024
#define L_N 1024
#define T_N 32
#define H_N 2048
#define K_TOP 64
#define O_N 256
#define NCOL (T_N * H_N) /* 65536 */

// ---------------- conversion: x -> bf16 ----------------
__global__ __launch_bounds__(256) void cvt_x_kernel(const float* __restrict__ x,
                                                    bf16_t* __restrict__ xb) {
  int i = (blockIdx.x * 256 + threadIdx.x) * 4;
  float4 v = *(const float4*)(x + i);
  bf16x4_t o;
  o[0] = (bf16_t)v.x; o[1] = (bf16_t)v.y; o[2] = (bf16_t)v.z; o[3] = (bf16_t)v.w;
  *(bf16x4_t*)(xb + i) = o;
}

// -------- conversion+transpose: Wt [T,L,H] f32 -> WT [T,H,L] bf16 --------
__global__ __launch_bounds__(256) void cvt_w_kernel(const float* __restrict__ W,
                                                    bf16_t* __restrict__ WT) {
  __shared__ float tile[64][65];
  int t = blockIdx.z;
  int h0 = blockIdx.x * 64;
  int l0 = blockIdx.y * 64;
  const float* src = W + (size_t)t * L_N * H_N;
  int hx = threadIdx.x & 63;
  int ly = threadIdx.x >> 6;
#pragma unroll
  for (int r = 0; r < 64; r += 4)
    tile[ly + r][hx] = src[(size_t)(l0 + ly + r) * H_N + h0 + hx];
  __syncthreads();
  bf16_t* dst = WT + (size_t)t * H_N * L_N;
  int lx = (threadIdx.x & 31) * 2;
  int hy = threadIdx.x >> 5;
#pragma unroll
  for (int r = 0; r < 64; r += 8) {
    int h = hy + r;
    bf16x2_t o;
    o[0] = (bf16_t)tile[lx][h];
    o[1] = (bf16_t)tile[lx + 1][h];
    *(bf16x2_t*)(dst + (size_t)(h0 + h) * L_N + l0 + lx) = o;
  }
}

// ---------------- GEMM1: hidden[b, t*2048+h] = sum_l x[b,l]*W[t,l,h] ----------------
#define BM 128
#define BN 128
#define BK 32

__device__ __forceinline__ void async_load16(const void* g, void* l) {
  __builtin_amdgcn_global_load_lds((const __attribute__((address_space(1))) void*)g,
                                   (__attribute__((address_space(3))) void*)l,
                                   16, 0, 0);
}

template <typename HT>
__global__ __launch_bounds__(256) void gemm1_kernel(const bf16_t* __restrict__ Xb,
                                                    const bf16_t* __restrict__ WT,
                                                    HT* __restrict__ hidden) {
  __shared__ bf16_t As[BM][BK]; // [m][k], row = 64 B
  __shared__ bf16_t Bs[BN][BK]; // [n][k], row = 64 B  (WT is already [n][k] in global)
  int tid = threadIdx.x;
  int wave = tid >> 6;
  int lane = tid & 63;
  int bid = blockIdx.x;
  int m0 = (bid & 7) * BM;      // 8 row tiles over B=1024
  int nbase = (bid >> 3) * BN;  // 512 col tiles over T*H=65536

  const bf16_t* Aptr = Xb + (size_t)m0 * L_N;
  const bf16_t* Bptr = WT + (size_t)nbase * L_N;

  // staging: lane i copies 16 B; wave covers 16 contiguous 64 B LDS rows
  int srow = lane >> 2;
  int scol = lane & 3;
  size_t soff = (size_t)(wave * 16 + srow) * L_N + scol * 8;

  f32x4_t acc[4][4];
  f32x4_t zero = {0.f, 0.f, 0.f, 0.f};
#pragma unroll
  for (int i = 0; i < 4; i++)
#pragma unroll
    for (int j = 0; j < 4; j++) acc[i][j] = zero;

  int wm = wave >> 1, wn = wave & 1;
  int fr = lane & 15;
  int fq = lane >> 4;

  for (int k0 = 0; k0 < L_N; k0 += BK) {
    const bf16_t* ga = Aptr + soff + k0;
    const bf16_t* gb = Bptr + soff + k0;
    async_load16(ga, &As[wave * 16][0]);
    async_load16(ga + 64 * L_N, &As[64 + wave * 16][0]);
    async_load16(gb, &Bs[wave * 16][0]);
    async_load16(gb + 64 * L_N, &Bs[64 + wave * 16][0]);
    __syncthreads();
    bf16x8_t af[4], bfv[4];
#pragma unroll
    for (int i = 0; i < 4; i++)
      af[i] = *(const bf16x8_t*)&As[wm * 64 + i * 16 + fr][fq * 8];
#pragma unroll
    for (int j = 0; j < 4; j++)
      bfv[j] = *(const bf16x8_t*)&Bs[wn * 64 + j * 16 + fr][fq * 8];
#pragma unroll
    for (int i = 0; i < 4; i++)
#pragma unroll
      for (int j = 0; j < 4; j++)
        acc[i][j] = __builtin_amdgcn_mfma_f32_16x16x32_bf16(af[i], bfv[j], acc[i][j], 0, 0, 0);
    __syncthreads();
  }

  // C/D layout: col = lane&15, row = (lane>>4)*4 + r  [verified m89/m91]
#pragma unroll
  for (int i = 0; i < 4; i++) {
    int gm = m0 + wm * 64 + i * 16 + fq * 4;
#pragma unroll
    for (int j = 0; j < 4; j++) {
      int gn = nbase + wn * 64 + j * 16 + fr;
      HT* outp = hidden + (size_t)gm * NCOL + gn;
#pragma unroll
      for (int r = 0; r < 4; r++) outp[(size_t)r * NCOL] = (HT)acc[i][j][r];
    }
  }
}

// ---------------- fused top-64 + dense + GELU + LN ----------------
// One wave per (b,t) row; waves fully independent (no __syncthreads).

__device__ __forceinline__ float wave_reduce_sum(float v) {
#pragma unroll
  for (int off = 32; off > 0; off >>= 1) v += __shfl_xor(v, off);
  return v;
}

// order-preserving float->uint key and inverse
__device__ __forceinline__ unsigned f2key(float f) {
  unsigned u = __float_as_uint(f);
  return u ^ ((u >> 31) ? 0xFFFFFFFFu : 0x80000000u);
}
__device__ __forceinline__ float key2f(unsigned k) {
  return __uint_as_float(k ^ ((k >> 31) ? 0x80000000u : 0xFFFFFFFFu));
}

__device__ __forceinline__ int lanes_below(unsigned long long m) {
  return (int)__builtin_amdgcn_mbcnt_hi((unsigned)(m >> 32),
                                        __builtin_amdgcn_mbcnt_lo((unsigned)m, 0u));
}

__device__ __forceinline__ void load_keys(const float* __restrict__ row, int lane,
                                          unsigned key[32]) {
  const float4* r4 = (const float4*)row;
  float4 v[8];
#pragma unroll
  for (int q = 0; q < 8; q++) v[q] = r4[lane + 64 * q];
#pragma unroll
  for (int q = 0; q < 8; q++) {
    key[q * 4 + 0] = f2key(v[q].x);
    key[q * 4 + 1] = f2key(v[q].y);
    key[q * 4 + 2] = f2key(v[q].z);
    key[q * 4 + 3] = f2key(v[q].w);
  }
}

__device__ __forceinline__ void load_keys(const bf16_t* __restrict__ row, int lane,
                                          unsigned key[32]) {
  const bf16x8_t* r8 = (const bf16x8_t*)row;
  bf16x8_t v[4];
#pragma unroll
  for (int q = 0; q < 4; q++) v[q] = r8[lane + 64 * q];
#pragma unroll
  for (int q = 0; q < 4; q++)
#pragma unroll
    for (int j = 0; j < 8; j++) key[q * 8 + j] = f2key((float)v[q][j]);
}

// launch_bounds(256,2): 128-VGPR budget. (256,4) capped at 64 VGPRs and
// spilled key[32] to scratch -> 1.7 GB scratch write traffic (R1 post-mortem).
template <typename HT>
__global__ __launch_bounds__(256, 2) void topk_tail_kernel(
    const HT* __restrict__ hidden, const float* __restrict__ Wd,
    const float* __restrict__ bd, const float* __restrict__ gamma,
    const float* __restrict__ beta, float* __restrict__ out) {
  __shared__ unsigned slots[4][K_TOP];
  int t = blockIdx.y;
  int wave = threadIdx.x >> 6;
  int lane = threadIdx.x & 63;
  int b = blockIdx.x * 4 + wave;

  unsigned key[32];
  load_keys(hidden + (size_t)b * NCOL + (size_t)t * H_N, lane, key);

  // exact 64th-largest key: largest thr with count(key >= thr) >= 64
  unsigned thr = 0;
  for (int bit = 31; bit >= 0; --bit) {
    unsigned cand = thr | (1u << bit);
    int c = 0;
#pragma unroll
    for (int i = 0; i < 32; i++) c += (int)__popcll(__ballot(key[i] >= cand));
    if (c >= K_TOP) thr = cand; // wave-uniform
  }

  // compaction via ballot prefix (no atomics, wave-local LDS only)
  int base = 0;
#pragma unroll
  for (int i = 0; i < 32; i++) {
    bool p = key[i] > thr;
    unsigned long long m = __ballot(p);
    if (p) slots[wave][base + lanes_below(m)] = key[i];
    base += (int)__popcll(m);
  }
#pragma unroll
  for (int i = 0; i < 32; i++) {
    bool p = key[i] == thr;
    unsigned long long m = __ballot(p);
    if (p) {
      int pos = base + lanes_below(m);
      if (pos < K_TOP) slots[wave][pos] = key[i];
    }
    base += (int)__popcll(m);
  }

  // 64-lane register bitonic sort, descending (unsigned keys)
  unsigned g = slots[wave][lane];
#pragma unroll
  for (int k = 2; k <= 64; k <<= 1) {
#pragma unroll
    for (int j = k >> 1; j > 0; j >>= 1) {
      unsigned other = (unsigned)__shfl_xor((int)g, j);
      bool keep_max = (((lane & k) == 0) != ((lane & j) != 0));
      unsigned mx = g > other ? g : other;
      unsigned mn = g > other ? other : g;
      g = keep_max ? mx : mn;
    }
  }
  float gv = key2f(g); // lane holds g_sorted[lane]

  // dense: y[n] = sum_k g_k * Wd[t,k,n] + b[t,n]   (fp32, fully unrolled)
  const float* wt = Wd + (size_t)t * K_TOP * O_N;
  float y0 = bd[t * O_N + lane];
  float y1 = bd[t * O_N + 64 + lane];
  float y2 = bd[t * O_N + 128 + lane];
  float y3 = bd[t * O_N + 192 + lane];
#pragma unroll
  for (int k = 0; k < K_TOP; k++) {
    float gk = __shfl(gv, k); // literal k -> v_readlane broadcast
    const float* wr = wt + k * O_N + lane;
    y0 = fmaf(gk, wr[0], y0);
    y1 = fmaf(gk, wr[64], y1);
    y2 = fmaf(gk, wr[128], y2);
    y3 = fmaf(gk, wr[192], y3);
  }
  // exact GELU
  const float is2 = 0.70710678118654752f;
  y0 = 0.5f * y0 * (1.f + erff(y0 * is2));
  y1 = 0.5f * y1 * (1.f + erff(y1 * is2));
  y2 = 0.5f * y2 * (1.f + erff(y2 * is2));
  y3 = 0.5f * y3 * (1.f + erff(y3 * is2));
  // LayerNorm over 256
  float mean = wave_reduce_sum(y0 + y1 + y2 + y3) * (1.f / 256.f);
  float d0 = y0 - mean, d1 = y1 - mean, d2 = y2 - mean, d3 = y3 - mean;
  float var = wave_reduce_sum(d0 * d0 + d1 * d1 + d2 * d2 + d3 * d3) * (1.f / 256.f);
  float rstd = rsqrtf(var + 1e-6f);
  float* op = out + (size_t)b * (T_N * O_N) + (size_t)t * O_N;
  const float* gm = gamma + t * O_N;
  const float* bt = beta + t * O_N;
  op[lane] = d0 * rstd * gm[lane] + bt[lane];
  op[64 + lane] = d1 * rstd * gm[64 + lane] + bt[64 + lane];
  op[128 + lane] = d2 * rstd * gm[128 + lane] + bt[128 + lane];
  op[192 + lane] = d3 * rstd * gm[192 + lane] + bt[192 + lane];
}

// ---------------- launch ----------------
extern "C" void kernel_launch(void* const* d_in, const int* in_sizes, int n_in,
                              void* d_out, int out_size, void* d_ws, size_t ws_size,
                              hipStream_t stream) {
  const float* x = (const float*)d_in[0];
  const float* Wt = (const float*)d_in[1];
  const float* Wd = (const float*)d_in[2];
  const float* bd = (const float*)d_in[3];
  const float* gamma = (const float*)d_in[4];
  const float* beta = (const float*)d_in[5];
  float* out = (float*)d_out;

  char* ws = (char*)d_ws;
  size_t sz_wt = (size_t)T_N * H_N * L_N * 2; // 128 MB
  size_t sz_x = (size_t)B_N * L_N * 2;        // 2 MB
  size_t off_h = sz_wt + sz_x;
  size_t sz_h_f32 = (size_t)B_N * NCOL * 4;   // 256 MB

  bf16_t* WTb = (bf16_t*)ws;
  bf16_t* Xb = (bf16_t*)(ws + sz_wt);

  cvt_x_kernel<<<B_N * L_N / 1024, 256, 0, stream>>>(x, Xb);
  cvt_w_kernel<<<dim3(H_N / 64, L_N / 64, T_N), 256, 0, stream>>>(Wt, WTb);

  if (ws_size >= off_h + sz_h_f32) {
    float* hidden = (float*)(ws + off_h);
    gemm1_kernel<float><<<4096, 256, 0, stream>>>(Xb, WTb, hidden);
    topk_tail_kernel<float><<<dim3(B_N / 4, T_N), 256, 0, stream>>>(
        hidden, Wd, bd, gamma, beta, out);
  } else { // fall back to bf16 hidden (270 MB total ws)
    bf16_t* hidden = (bf16_t*)(ws + off_h);
    gemm1_kernel<bf16_t><<<4096, 256, 0, stream>>>(Xb, WTb, hidden);
    topk_tail_kernel<bf16_t><<<dim3(B_N / 4, T_N), 256, 0, stream>>>(
        hidden, Wd, bd, gamma, beta, out);
  }
}